// Round 9
// baseline (348.617 us; speedup 1.0000x reference)
//
#include <hip/hip_runtime.h>
#include <hip/hip_bf16.h>

#define B_   2
#define S_   2048
#define DM   1024
#define NH   16
#define Mdim 4096
#define Kdim 1024

typedef __attribute__((ext_vector_type(8))) short bf16x8;
typedef __attribute__((ext_vector_type(4))) short bf16x4;
typedef __attribute__((ext_vector_type(4))) float f32x4;

__device__ __forceinline__ short f2b(float x) {
  union { __hip_bfloat16 h; short s; } u;
  u.h = __float2bfloat16(x);
  return u.s;
}

// Blocked GEMM operand layout: [row/128][k/32][chunk=k%32/8][row%128][k%8]
__device__ __forceinline__ size_t blk_idx(int row, int k) {
  return ((size_t)(row >> 7) * 32 + (k >> 5)) * 4096 + ((k >> 3) & 3) * 1024 +
         (row & 127) * 8 + (k & 7);
}

// async global->LDS, 16 B/lane; LDS dst = wave-uniform base + lane*16
__device__ __forceinline__ void async_copy16(const void* g, void* l) {
  __builtin_amdgcn_global_load_lds(
      (const __attribute__((address_space(1))) unsigned int*)g,
      (__attribute__((address_space(3))) unsigned int*)l, 16, 0, 0);
}

// ---------------------------------------------------------------------------
// Batched fp32 -> bf16 conversion into the blocked layout (7 tensors).
struct Cvt7 {
  const float* src[7];
  ushort* dst[7];
  int n[7];
};

__global__ __launch_bounds__(256) void cvt_all(Cvt7 c) {
  const int ten = blockIdx.y;
  const int base = (blockIdx.x * 256 + threadIdx.x) * 8;
  if (base >= c.n[ten]) return;
  const float* s = c.src[ten] + base;
  float4 a = *(const float4*)s;
  float4 b = *(const float4*)(s + 4);
  bf16x8 r;
  r[0] = f2b(a.x); r[1] = f2b(a.y); r[2] = f2b(a.z); r[3] = f2b(a.w);
  r[4] = f2b(b.x); r[5] = f2b(b.y); r[6] = f2b(b.z); r[7] = f2b(b.w);
  const int row = base >> 10, k = base & 1023;  // K = 1024 for all operands
  *(bf16x8*)(c.dst[ten] + blk_idx(row, k)) = r;
}

// ---------------------------------------------------------------------------
// Pack mask to bits: mpk[(b*S+q)*32 + seg] = ballot over 64 keys.
__global__ __launch_bounds__(256) void pack_mask(const int* __restrict__ mask,
                                                 unsigned long long* __restrict__ mpk) {
  const int gw = (blockIdx.x * 256 + threadIdx.x) >> 6;
  const int lane = threadIdx.x & 63;
  const int mv = mask[(size_t)gw * 64 + lane];
  const unsigned long long bits = __ballot(mv != 0);
  if (lane == 0) mpk[gw] = bits;
}

// ---------------------------------------------------------------------------
// Pipelined GEMM: C[4096,1024] = A @ W^T + bias, *scale.  A,W in blocked
// layout (blk_idx). 128x128 tile, BK=32, double-buffered LDS, contiguous
// global_load_lds staging. 4 waves 2x2; wave = 64x64 (4x4 frags).
// MODE 0: float normal; 1: bf16 normal; 2: K-swizzle scatter; 3: V-swizzle.
template <int MODE>
__global__ __launch_bounds__(256) void gemm_pipe(const ushort* __restrict__ A,
                                                 const ushort* __restrict__ W,
                                                 const float* __restrict__ bias,
                                                 void* __restrict__ Cv, float scale) {
  const int t = threadIdx.x;
  const int w = t >> 6, lane = t & 63;
  const int quad = lane >> 4, r16 = lane & 15;
  const int wr = w >> 1, wc = w & 1;
  const int row0 = blockIdx.x * 128, col0 = blockIdx.y * 128;

  __shared__ alignas(16) ushort a_s[2][4096];  // [chunk][row%128][8]
  __shared__ alignas(16) ushort b_s[2][4096];

  // contiguous staging: per k-block, A-tile = 4096 u16 (8 KB) at fixed base
  const ushort* Ab = A + (size_t)blockIdx.x * 32 * 4096 + (size_t)t * 8;
  const ushort* Wb = W + (size_t)blockIdx.y * 32 * 4096 + (size_t)t * 8;
  const int lo0 = w * 512, lo1 = 2048 + w * 512;

#define STAGE(buf, kb)                                   \
  do {                                                   \
    const size_t off = (size_t)(kb) * 4096;              \
    async_copy16(Ab + off, &a_s[buf][lo0]);              \
    async_copy16(Ab + off + 2048, &a_s[buf][lo1]);       \
    async_copy16(Wb + off, &b_s[buf][lo0]);              \
    async_copy16(Wb + off + 2048, &b_s[buf][lo1]);       \
  } while (0)

  f32x4 acc[4][4];
#pragma unroll
  for (int mt = 0; mt < 4; ++mt)
#pragma unroll
    for (int nt = 0; nt < 4; ++nt) acc[mt][nt] = (f32x4){0.f, 0.f, 0.f, 0.f};

  STAGE(0, 0);
  int cur = 0;
  for (int kb = 0; kb < 32; ++kb) {
    __syncthreads();  // waits: copies into buf[cur] + previous ds_reads
    if (kb + 1 < 32) STAGE(1 - cur, kb + 1);  // lands during this compute

    bf16x8 af[4], bfr[4];
#pragma unroll
    for (int mt = 0; mt < 4; ++mt)
      af[mt] = *(const bf16x8*)&a_s[cur][quad * 1024 + (wr * 64 + mt * 16 + r16) * 8];
#pragma unroll
    for (int nt = 0; nt < 4; ++nt)
      bfr[nt] = *(const bf16x8*)&b_s[cur][quad * 1024 + (wc * 64 + nt * 16 + r16) * 8];
#pragma unroll
    for (int mt = 0; mt < 4; ++mt)
#pragma unroll
      for (int nt = 0; nt < 4; ++nt)
        acc[mt][nt] = __builtin_amdgcn_mfma_f32_16x16x32_bf16(af[mt], bfr[nt],
                                                              acc[mt][nt], 0, 0, 0);
    cur ^= 1;
  }
#undef STAGE

  // epilogue: C/D layout col=lane&15, row=quad*4+reg
#pragma unroll
  for (int mt = 0; mt < 4; ++mt) {
#pragma unroll
    for (int nt = 0; nt < 4; ++nt) {
      const int col = col0 + wc * 64 + nt * 16 + r16;
      const float bv = bias[col];
      const int rowb = row0 + wr * 64 + mt * 16 + quad * 4;
#pragma unroll
      for (int i = 0; i < 4; ++i) {
        const float v = (acc[mt][nt][i] + bv) * scale;
        const int row = rowb + i;
        if (MODE == 0) {
          ((float*)Cv)[(size_t)row * DM + col] = v;
        } else if (MODE == 1) {
          ((ushort*)Cv)[(size_t)row * DM + col] = (ushort)f2b(v);
        } else if (MODE == 2) {
          // Kg[(bh*S+s)*64 + ((d/8)^(s&7))*8 + d&7]
          const int bb = row >> 11, s = row & (S_ - 1);
          const int hh = col >> 6, d = col & 63;
          const size_t idx = ((size_t)(bb * NH + hh) * S_ + s) * 64 +
                             (((d >> 3) ^ (s & 7)) * 8) + (d & 7);
          ((ushort*)Cv)[idx] = (ushort)f2b(v);
        } else {
          // Vg[(bh*64+d)*S + (s&~63) + (((s/8)&7)^(d&7))*8 + s&7]
          const int bb = row >> 11, s = row & (S_ - 1);
          const int hh = col >> 6, d = col & 63;
          const size_t idx = ((size_t)(bb * NH + hh) * 64 + d) * S_ + (s & ~63) +
                             ((((s >> 3) & 7) ^ (d & 7)) * 8) + (s & 7);
          ((ushort*)Cv)[idx] = (ushort)f2b(v);
        }
      }
    }
  }
}

// ---------------------------------------------------------------------------
// MFMA flash attention, no-max softmax (Q pre-scaled by 1/8; |s| bounded).
// Block = (b,h,64 q-rows); 4 waves; KT=64. Qp bf16 [B*S,DM];
// Kg/Vg bf16 pre-swizzled; mpk packed mask. Output: blocked layout (blk_idx)
// to feed the final GEMM.
__global__ __launch_bounds__(256) void attn_mfma(const ushort* __restrict__ Qp,
                                                 const ushort* __restrict__ Kg,
                                                 const ushort* __restrict__ Vg,
                                                 const unsigned long long* __restrict__ mpk,
                                                 ushort* __restrict__ Oa) {
  const int bh = blockIdx.y;
  const int b = bh >> 4, h = bh & 15;
  const int q0 = blockIdx.x * 64;
  const int t = threadIdx.x;
  const int w = t >> 6, lane = t & 63, quad = lane >> 4, r16 = lane & 15;
  const size_t rb = (size_t)b * S_;

  __shared__ alignas(16) ushort k_s[64 * 64];
  __shared__ alignas(16) ushort vt_s[64 * 64];
  __shared__ alignas(16) ushort p_s[4][16 * 76];

  // Q fragment (A-layout: m=lane&15, k=quad*8+j)
  const ushort* qptr = Qp + (rb + q0 + w * 16 + r16) * DM + h * 64 + quad * 8;
  const bf16x8 aq0 = *(const bf16x8*)qptr;
  const bf16x8 aq1 = *(const bf16x8*)(qptr + 32);

  float l_i[4] = {0.f, 0.f, 0.f, 0.f};
  f32x4 oacc[4];
#pragma unroll
  for (int nt = 0; nt < 4; ++nt) oacc[nt] = (f32x4){0.f, 0.f, 0.f, 0.f};

  const ushort* kgb = Kg + (size_t)bh * S_ * 64 + (size_t)t * 8;
  const ushort* vgb = Vg + (size_t)bh * 64 * S_ + (size_t)(t >> 3) * S_ + (t & 7) * 8;
  ushort* kl0 = &k_s[w * 512];
  ushort* kl1 = &k_s[2048 + w * 512];
  ushort* vl0 = &vt_s[w * 512];
  ushort* vl1 = &vt_s[2048 + w * 512];

  const unsigned long long* mrowp = mpk + (rb + q0 + w * 16 + quad * 4) * 32;

  for (int kt = 0; kt < S_; kt += 64) {
    __syncthreads();
    async_copy16(kgb + (size_t)kt * 64, kl0);
    async_copy16(kgb + (size_t)(kt + 32) * 64, kl1);
    async_copy16(vgb + kt, vl0);
    async_copy16(vgb + (size_t)32 * S_ + kt, vl1);
    __syncthreads();

    // ---- S = Q K^T
    f32x4 sacc[4];
#pragma unroll
    for (int nt = 0; nt < 4; ++nt) {
      sacc[nt] = (f32x4){0.f, 0.f, 0.f, 0.f};
      const int krow = nt * 16 + r16;
      const bf16x8 b0 = *(const bf16x8*)&k_s[krow * 64 + ((quad ^ (krow & 7)) * 8)];
      const bf16x8 b1 = *(const bf16x8*)&k_s[krow * 64 + (((4 + quad) ^ (krow & 7)) * 8)];
      sacc[nt] = __builtin_amdgcn_mfma_f32_16x16x32_bf16(aq0, b0, sacc[nt], 0, 0, 0);
      sacc[nt] = __builtin_amdgcn_mfma_f32_16x16x32_bf16(aq1, b1, sacc[nt], 0, 0, 0);
    }

    // ---- mask bits + exp (no max-subtract; deferred l-reduction)
    const int seg = kt >> 6;
#pragma unroll
    for (int i = 0; i < 4; ++i) {
      const unsigned long long mbits = mrowp[i * 32 + seg];
      float ps = 0.f;
#pragma unroll
      for (int nt = 0; nt < 4; ++nt) {
        const unsigned int bit = (unsigned int)(mbits >> (nt * 16 + r16)) & 1u;
        const float p = bit ? __expf(sacc[nt][i]) : 0.f;
        ps += p;
        p_s[w][(quad * 4 + i) * 76 + nt * 16 + r16] = (ushort)f2b(p);
      }
      l_i[i] += ps;
    }

    // ---- O += P V
#pragma unroll
    for (int ks = 0; ks < 2; ++ks) {
      const bf16x4 lo = *(const bf16x4*)&p_s[w][r16 * 76 + ks * 32 + quad * 8];
      const bf16x4 hi = *(const bf16x4*)&p_s[w][r16 * 76 + ks * 32 + quad * 8 + 4];
      bf16x8 pa;
#pragma unroll
      for (int j = 0; j < 4; ++j) { pa[j] = lo[j]; pa[4 + j] = hi[j]; }
      const int kc = ks * 4 + quad;
#pragma unroll
      for (int nt = 0; nt < 4; ++nt) {
        const int dk = nt * 16 + r16;
        const bf16x8 vb = *(const bf16x8*)&vt_s[dk * 64 + ((kc ^ (dk & 7)) * 8)];
        oacc[nt] = __builtin_amdgcn_mfma_f32_16x16x32_bf16(pa, vb, oacc[nt], 0, 0, 0);
      }
    }
  }

  // ---- epilogue: reduce l, divide, store in blocked layout for final GEMM
#pragma unroll
  for (int i = 0; i < 4; ++i) {
    float l = l_i[i];
#pragma unroll
    for (int off = 1; off < 16; off <<= 1) l += __shfl_xor(l, off);
    l_i[i] = l;
  }
#pragma unroll
  for (int nt = 0; nt < 4; ++nt) {
#pragma unroll
    for (int i = 0; i < 4; ++i) {
      const int row = (int)rb + q0 + w * 16 + quad * 4 + i;
      const int col = h * 64 + nt * 16 + r16;
      Oa[blk_idx(row, col)] = (ushort)f2b(oacc[nt][i] / l_i[i]);
    }
  }
}

// ---------------------------------------------------------------------------
// Workspace = 56 MB (proven): qc,kc,vc | Qp,Kg,Vg | 4 weights.
// mpk (1 MB) overlays kc after the K-projection consumed it (stream-ordered).
extern "C" void kernel_launch(void* const* d_in, const int* in_sizes, int n_in,
                              void* d_out, int out_size, void* d_ws, size_t ws_size,
                              hipStream_t stream) {
  const int* mask = (const int*)d_in[3];
  const float* bq = (const float*)d_in[5];
  const float* bk = (const float*)d_in[7];
  const float* bv = (const float*)d_in[9];
  const float* bo = (const float*)d_in[11];

  const size_t NE = (size_t)B_ * S_ * DM;  // 4M
  const size_t NW = (size_t)DM * DM;       // 1M

  ushort* qc = (ushort*)d_ws;   // blocked
  ushort* kc = qc + NE;         // blocked
  ushort* vc = kc + NE;         // blocked
  ushort* Qp = vc + NE;         // [B*S, DM]
  ushort* Kg = Qp + NE;         // swizzled
  ushort* Vg = Kg + NE;         // swizzled transposed
  ushort* Wqc = Vg + NE;        // blocked weights
  ushort* Wkc = Wqc + NW;
  ushort* Wvc = Wkc + NW;
  ushort* Woc = Wvc + NW;
  unsigned long long* mpk = (unsigned long long*)kc;  // after kc consumed

  Cvt7 c;
  const int sidx[7] = {0, 1, 2, 4, 6, 8, 10};
  ushort* dsts[7] = {qc, kc, vc, Wqc, Wkc, Wvc, Woc};
  for (int i = 0; i < 7; ++i) {
    c.src[i] = (const float*)d_in[sidx[i]];
    c.dst[i] = dsts[i];
    c.n[i] = (i < 3) ? (int)NE : (int)NW;
  }
  cvt_all<<<dim3(2048, 7), 256, 0, stream>>>(c);

  dim3 gg(Mdim / 128, DM / 128);  // 32 x 8
  gemm_pipe<1><<<gg, 256, 0, stream>>>(qc, Wqc, bq, Qp, 0.125f);  // Q pre-scaled
  gemm_pipe<2><<<gg, 256, 0, stream>>>(kc, Wkc, bk, Kg, 1.0f);    // K swizzled
  gemm_pipe<3><<<gg, 256, 0, stream>>>(vc, Wvc, bv, Vg, 1.0f);    // V^T swizzled

  pack_mask<<<(B_ * S_ * (S_ / 64) * 64) / 256, 256, 0, stream>>>(mask, mpk);

  attn_mfma<<<dim3(S_ / 64, B_ * NH), 256, 0, stream>>>(Qp, Kg, Vg, mpk, qc);

  gemm_pipe<0><<<gg, 256, 0, stream>>>(qc, Woc, bo, (float*)d_out, 1.0f);
}

// Round 10
// 310.010 us; speedup vs baseline: 1.1245x; 1.1245x over previous
//
#include <hip/hip_runtime.h>
#include <hip/hip_bf16.h>

#define B_   2
#define S_   2048
#define DM   1024
#define NH   16
#define Mdim 4096
#define Kdim 1024

typedef __attribute__((ext_vector_type(8))) short bf16x8;
typedef __attribute__((ext_vector_type(4))) short bf16x4;
typedef __attribute__((ext_vector_type(4))) float f32x4;

__device__ __forceinline__ short f2b(float x) {
  union { __hip_bfloat16 h; short s; } u;
  u.h = __float2bfloat16(x);
  return u.s;
}

// Blocked GEMM operand layout: [row/128][k/32][row%128][k%32] (8 KB tiles).
// cvt writes 64B-coalesced; staging = contiguous 4 KB DMAs; frag ds_read_b128
// = contiguous 1 KB per wave (conflict-free).
__device__ __forceinline__ size_t blk_idx(int row, int k) {
  return ((size_t)(row >> 7) * 32 + (k >> 5)) * 4096 + (row & 127) * 32 + (k & 31);
}

// async global->LDS, 16 B/lane; LDS dst = wave-uniform base + lane*16
__device__ __forceinline__ void async_copy16(const void* g, void* l) {
  __builtin_amdgcn_global_load_lds(
      (const __attribute__((address_space(1))) unsigned int*)g,
      (__attribute__((address_space(3))) unsigned int*)l, 16, 0, 0);
}

// ---------------------------------------------------------------------------
// Batched fp32 -> bf16 conversion into the blocked layout (7 tensors).
struct Cvt7 {
  const float* src[7];
  ushort* dst[7];
  int n[7];
};

__global__ __launch_bounds__(256) void cvt_all(Cvt7 c) {
  const int ten = blockIdx.y;
  const int base = (blockIdx.x * 256 + threadIdx.x) * 8;
  if (base >= c.n[ten]) return;
  const float* s = c.src[ten] + base;
  float4 a = *(const float4*)s;
  float4 b = *(const float4*)(s + 4);
  bf16x8 r;
  r[0] = f2b(a.x); r[1] = f2b(a.y); r[2] = f2b(a.z); r[3] = f2b(a.w);
  r[4] = f2b(b.x); r[5] = f2b(b.y); r[6] = f2b(b.z); r[7] = f2b(b.w);
  const int row = base >> 10, k = base & 1023;  // K = 1024 for all operands
  *(bf16x8*)(c.dst[ten] + blk_idx(row, k)) = r;
}

// ---------------------------------------------------------------------------
// Pack mask to bits: mpk[(b*S+q)*32 + seg] = ballot over 64 keys.
__global__ __launch_bounds__(256) void pack_mask(const int* __restrict__ mask,
                                                 unsigned long long* __restrict__ mpk) {
  const int gw = (blockIdx.x * 256 + threadIdx.x) >> 6;
  const int lane = threadIdx.x & 63;
  const int mv = mask[(size_t)gw * 64 + lane];
  const unsigned long long bits = __ballot(mv != 0);
  if (lane == 0) mpk[gw] = bits;
}

// ---------------------------------------------------------------------------
// fill d_out with broadcast bias rows (before atomic split-K accumulation)
__global__ __launch_bounds__(256) void fill_bias(float* __restrict__ out,
                                                 const float* __restrict__ bias) {
  const int t = blockIdx.x * 256 + threadIdx.x;  // 1M float4 groups
  ((float4*)out)[t] = *(const float4*)&bias[(t * 4) & (DM - 1)];
}

// ---------------------------------------------------------------------------
// Merged Q/K/V projection GEMM: blockIdx.z selects tensor. 128x128 tile,
// BK=32, dbuf LDS, contiguous staging. Grid 32x8x3 = 768 blocks (3/CU).
// z=0: Qp bf16 [B*S,DM] pre-scaled 1/8; z=1: Kg swizzled; z=2: Vg swizzled^T.
struct Proj {
  const ushort* A[3];
  const ushort* W[3];
  const float* bias[3];
  ushort* out[3];
};

__global__ __launch_bounds__(256) void gemm_qkv(Proj p) {
  const int z = blockIdx.z;
  const int t = threadIdx.x;
  const int w = t >> 6, lane = t & 63;
  const int quad = lane >> 4, r16 = lane & 15;
  const int wr = w >> 1, wc = w & 1;
  const int row0 = blockIdx.x * 128, col0 = blockIdx.y * 128;

  __shared__ alignas(16) ushort a_s[2][4096];  // [row%128][k%32]
  __shared__ alignas(16) ushort b_s[2][4096];

  const ushort* Ab = p.A[z] + (size_t)blockIdx.x * 32 * 4096 + (size_t)t * 8;
  const ushort* Wb = p.W[z] + (size_t)blockIdx.y * 32 * 4096 + (size_t)t * 8;
  const int lo0 = w * 512, lo1 = 2048 + w * 512;

#define STAGE(buf, kb)                                  \
  do {                                                  \
    const size_t off = (size_t)(kb) * 4096;             \
    async_copy16(Ab + off, &a_s[buf][lo0]);             \
    async_copy16(Ab + off + 2048, &a_s[buf][lo1]);      \
    async_copy16(Wb + off, &b_s[buf][lo0]);             \
    async_copy16(Wb + off + 2048, &b_s[buf][lo1]);      \
  } while (0)

  f32x4 acc[4][4];
#pragma unroll
  for (int mt = 0; mt < 4; ++mt)
#pragma unroll
    for (int nt = 0; nt < 4; ++nt) acc[mt][nt] = (f32x4){0.f, 0.f, 0.f, 0.f};

  STAGE(0, 0);
  int cur = 0;
  for (int kb = 0; kb < 32; ++kb) {
    __syncthreads();
    if (kb + 1 < 32) STAGE(1 - cur, kb + 1);
    bf16x8 af[4], bfr[4];
#pragma unroll
    for (int mt = 0; mt < 4; ++mt)
      af[mt] = *(const bf16x8*)&a_s[cur][(wr * 64 + mt * 16 + r16) * 32 + quad * 8];
#pragma unroll
    for (int nt = 0; nt < 4; ++nt)
      bfr[nt] = *(const bf16x8*)&b_s[cur][(wc * 64 + nt * 16 + r16) * 32 + quad * 8];
#pragma unroll
    for (int mt = 0; mt < 4; ++mt)
#pragma unroll
      for (int nt = 0; nt < 4; ++nt)
        acc[mt][nt] = __builtin_amdgcn_mfma_f32_16x16x32_bf16(af[mt], bfr[nt],
                                                              acc[mt][nt], 0, 0, 0);
    cur ^= 1;
  }

  // epilogue: C/D layout col=lane&15, row=quad*4+reg
  const float scale = (z == 0) ? 0.125f : 1.0f;
  ushort* Cv = p.out[z];
#pragma unroll
  for (int mt = 0; mt < 4; ++mt) {
#pragma unroll
    for (int nt = 0; nt < 4; ++nt) {
      const int col = col0 + wc * 64 + nt * 16 + r16;
      const float bv = p.bias[z][col];
      const int rowb = row0 + wr * 64 + mt * 16 + quad * 4;
#pragma unroll
      for (int i = 0; i < 4; ++i) {
        const float v = (acc[mt][nt][i] + bv) * scale;
        const int row = rowb + i;
        const int bb = row >> 11, s = row & (S_ - 1);
        const int hh = col >> 6, d = col & 63;
        if (z == 0) {
          Cv[(size_t)row * DM + col] = (ushort)f2b(v);
        } else if (z == 1) {
          // Kg[(bh*S+s)*64 + ((d/8)^(s&7))*8 + d&7]
          const size_t idx = ((size_t)(bb * NH + hh) * S_ + s) * 64 +
                             (((d >> 3) ^ (s & 7)) * 8) + (d & 7);
          Cv[idx] = (ushort)f2b(v);
        } else {
          // Vg[(bh*64+d)*S + (s&~63) + (((s/8)&7)^(d&7))*8 + s&7]
          const size_t idx = ((size_t)(bb * NH + hh) * 64 + d) * S_ + (s & ~63) +
                             ((((s >> 3) & 7) ^ (d & 7)) * 8) + (s & 7);
          Cv[idx] = (ushort)f2b(v);
        }
      }
    }
  }
}

// ---------------------------------------------------------------------------
// Final GEMM, split-K=2 (grid 32x8x2 = 512 blocks, 2/CU): accumulates into
// bias-prefilled d_out via HW fp32 atomics.
__global__ __launch_bounds__(256) void gemm_out(const ushort* __restrict__ A,
                                                const ushort* __restrict__ W,
                                                float* __restrict__ out) {
  const int kz = blockIdx.z;
  const int t = threadIdx.x;
  const int w = t >> 6, lane = t & 63;
  const int quad = lane >> 4, r16 = lane & 15;
  const int wr = w >> 1, wc = w & 1;
  const int row0 = blockIdx.x * 128, col0 = blockIdx.y * 128;

  __shared__ alignas(16) ushort a_s[2][4096];
  __shared__ alignas(16) ushort b_s[2][4096];

  const ushort* Ab = A + (size_t)blockIdx.x * 32 * 4096 + (size_t)t * 8;
  const ushort* Wb = W + (size_t)blockIdx.y * 32 * 4096 + (size_t)t * 8;
  const int lo0 = w * 512, lo1 = 2048 + w * 512;

  f32x4 acc[4][4];
#pragma unroll
  for (int mt = 0; mt < 4; ++mt)
#pragma unroll
    for (int nt = 0; nt < 4; ++nt) acc[mt][nt] = (f32x4){0.f, 0.f, 0.f, 0.f};

  const int kb0 = kz * 16;
  STAGE(0, kb0);
  int cur = 0;
  for (int kb = kb0; kb < kb0 + 16; ++kb) {
    __syncthreads();
    if (kb + 1 < kb0 + 16) STAGE(1 - cur, kb + 1);
    bf16x8 af[4], bfr[4];
#pragma unroll
    for (int mt = 0; mt < 4; ++mt)
      af[mt] = *(const bf16x8*)&a_s[cur][(wr * 64 + mt * 16 + r16) * 32 + quad * 8];
#pragma unroll
    for (int nt = 0; nt < 4; ++nt)
      bfr[nt] = *(const bf16x8*)&b_s[cur][(wc * 64 + nt * 16 + r16) * 32 + quad * 8];
#pragma unroll
    for (int mt = 0; mt < 4; ++mt)
#pragma unroll
      for (int nt = 0; nt < 4; ++nt)
        acc[mt][nt] = __builtin_amdgcn_mfma_f32_16x16x32_bf16(af[mt], bfr[nt],
                                                              acc[mt][nt], 0, 0, 0);
    cur ^= 1;
  }
#undef STAGE

#pragma unroll
  for (int mt = 0; mt < 4; ++mt) {
#pragma unroll
    for (int nt = 0; nt < 4; ++nt) {
      const int col = col0 + wc * 64 + nt * 16 + r16;
      const int rowb = row0 + wr * 64 + mt * 16 + quad * 4;
#pragma unroll
      for (int i = 0; i < 4; ++i)
        unsafeAtomicAdd(&out[(size_t)(rowb + i) * DM + col], acc[mt][nt][i]);
    }
  }
}

// ---------------------------------------------------------------------------
// MFMA flash attention (unchanged structure; epilogue writes blocked layout).
__global__ __launch_bounds__(256) void attn_mfma(const ushort* __restrict__ Qp,
                                                 const ushort* __restrict__ Kg,
                                                 const ushort* __restrict__ Vg,
                                                 const unsigned long long* __restrict__ mpk,
                                                 ushort* __restrict__ Oa) {
  const int bh = blockIdx.y;
  const int b = bh >> 4, h = bh & 15;
  const int q0 = blockIdx.x * 64;
  const int t = threadIdx.x;
  const int w = t >> 6, lane = t & 63, quad = lane >> 4, r16 = lane & 15;
  const size_t rb = (size_t)b * S_;

  __shared__ alignas(16) ushort k_s[64 * 64];
  __shared__ alignas(16) ushort vt_s[64 * 64];
  __shared__ alignas(16) ushort p_s[4][16 * 76];

  const ushort* qptr = Qp + (rb + q0 + w * 16 + r16) * DM + h * 64 + quad * 8;
  const bf16x8 aq0 = *(const bf16x8*)qptr;
  const bf16x8 aq1 = *(const bf16x8*)(qptr + 32);

  float l_i[4] = {0.f, 0.f, 0.f, 0.f};
  f32x4 oacc[4];
#pragma unroll
  for (int nt = 0; nt < 4; ++nt) oacc[nt] = (f32x4){0.f, 0.f, 0.f, 0.f};

  const ushort* kgb = Kg + (size_t)bh * S_ * 64 + (size_t)t * 8;
  const ushort* vgb = Vg + (size_t)bh * 64 * S_ + (size_t)(t >> 3) * S_ + (t & 7) * 8;
  ushort* kl0 = &k_s[w * 512];
  ushort* kl1 = &k_s[2048 + w * 512];
  ushort* vl0 = &vt_s[w * 512];
  ushort* vl1 = &vt_s[2048 + w * 512];

  const unsigned long long* mrowp = mpk + (rb + q0 + w * 16 + quad * 4) * 32;

  for (int kt = 0; kt < S_; kt += 64) {
    __syncthreads();
    async_copy16(kgb + (size_t)kt * 64, kl0);
    async_copy16(kgb + (size_t)(kt + 32) * 64, kl1);
    async_copy16(vgb + kt, vl0);
    async_copy16(vgb + (size_t)32 * S_ + kt, vl1);
    __syncthreads();

    f32x4 sacc[4];
#pragma unroll
    for (int nt = 0; nt < 4; ++nt) {
      sacc[nt] = (f32x4){0.f, 0.f, 0.f, 0.f};
      const int krow = nt * 16 + r16;
      const bf16x8 b0 = *(const bf16x8*)&k_s[krow * 64 + ((quad ^ (krow & 7)) * 8)];
      const bf16x8 b1 = *(const bf16x8*)&k_s[krow * 64 + (((4 + quad) ^ (krow & 7)) * 8)];
      sacc[nt] = __builtin_amdgcn_mfma_f32_16x16x32_bf16(aq0, b0, sacc[nt], 0, 0, 0);
      sacc[nt] = __builtin_amdgcn_mfma_f32_16x16x32_bf16(aq1, b1, sacc[nt], 0, 0, 0);
    }

    const int seg = kt >> 6;
#pragma unroll
    for (int i = 0; i < 4; ++i) {
      const unsigned long long mbits = mrowp[i * 32 + seg];
      float ps = 0.f;
#pragma unroll
      for (int nt = 0; nt < 4; ++nt) {
        const unsigned int bit = (unsigned int)(mbits >> (nt * 16 + r16)) & 1u;
        const float p = bit ? __expf(sacc[nt][i]) : 0.f;
        ps += p;
        p_s[w][(quad * 4 + i) * 76 + nt * 16 + r16] = (ushort)f2b(p);
      }
      l_i[i] += ps;
    }

#pragma unroll
    for (int ks = 0; ks < 2; ++ks) {
      const bf16x4 lo = *(const bf16x4*)&p_s[w][r16 * 76 + ks * 32 + quad * 8];
      const bf16x4 hi = *(const bf16x4*)&p_s[w][r16 * 76 + ks * 32 + quad * 8 + 4];
      bf16x8 pa;
#pragma unroll
      for (int j = 0; j < 4; ++j) { pa[j] = lo[j]; pa[4 + j] = hi[j]; }
      const int kc = ks * 4 + quad;
#pragma unroll
      for (int nt = 0; nt < 4; ++nt) {
        const int dk = nt * 16 + r16;
        const bf16x8 vb = *(const bf16x8*)&vt_s[dk * 64 + ((kc ^ (dk & 7)) * 8)];
        oacc[nt] = __builtin_amdgcn_mfma_f32_16x16x32_bf16(pa, vb, oacc[nt], 0, 0, 0);
      }
    }
  }

#pragma unroll
  for (int i = 0; i < 4; ++i) {
    float l = l_i[i];
#pragma unroll
    for (int off = 1; off < 16; off <<= 1) l += __shfl_xor(l, off);
    l_i[i] = l;
  }
#pragma unroll
  for (int nt = 0; nt < 4; ++nt) {
#pragma unroll
    for (int i = 0; i < 4; ++i) {
      const int row = (int)rb + q0 + w * 16 + quad * 4 + i;
      const int col = h * 64 + nt * 16 + r16;
      Oa[blk_idx(row, col)] = (ushort)f2b(oacc[nt][i] / l_i[i]);
    }
  }
}

// ---------------------------------------------------------------------------
// Workspace = 56 MB (proven): qc,kc,vc | Qp,Kg,Vg | 4 weights.
// mpk (1 MB) overlays kc after the projections consumed it (stream-ordered).
extern "C" void kernel_launch(void* const* d_in, const int* in_sizes, int n_in,
                              void* d_out, int out_size, void* d_ws, size_t ws_size,
                              hipStream_t stream) {
  const int* mask = (const int*)d_in[3];
  const float* bo = (const float*)d_in[11];

  const size_t NE = (size_t)B_ * S_ * DM;  // 4M
  const size_t NW = (size_t)DM * DM;       // 1M

  ushort* qc = (ushort*)d_ws;   // blocked
  ushort* kc = qc + NE;
  ushort* vc = kc + NE;
  ushort* Qp = vc + NE;         // [B*S, DM]
  ushort* Kg = Qp + NE;         // swizzled
  ushort* Vg = Kg + NE;         // swizzled transposed
  ushort* Wqc = Vg + NE;        // blocked weights
  ushort* Wkc = Wqc + NW;
  ushort* Wvc = Wkc + NW;
  ushort* Woc = Wvc + NW;
  unsigned long long* mpk = (unsigned long long*)kc;

  Cvt7 c;
  const int sidx[7] = {0, 1, 2, 4, 6, 8, 10};
  ushort* dsts[7] = {qc, kc, vc, Wqc, Wkc, Wvc, Woc};
  for (int i = 0; i < 7; ++i) {
    c.src[i] = (const float*)d_in[sidx[i]];
    c.dst[i] = dsts[i];
    c.n[i] = (i < 3) ? (int)NE : (int)NW;
  }
  cvt_all<<<dim3(2048, 7), 256, 0, stream>>>(c);

  Proj p;
  p.A[0] = qc;  p.A[1] = kc;  p.A[2] = vc;
  p.W[0] = Wqc; p.W[1] = Wkc; p.W[2] = Wvc;
  p.bias[0] = (const float*)d_in[5];
  p.bias[1] = (const float*)d_in[7];
  p.bias[2] = (const float*)d_in[9];
  p.out[0] = Qp; p.out[1] = Kg; p.out[2] = Vg;
  gemm_qkv<<<dim3(Mdim / 128, DM / 128, 3), 256, 0, stream>>>(p);

  pack_mask<<<(B_ * S_ * (S_ / 64) * 64) / 256, 256, 0, stream>>>(mask, mpk);

  attn_mfma<<<dim3(S_ / 64, B_ * NH), 256, 0, stream>>>(Qp, Kg, Vg, mpk, qc);

  fill_bias<<<(int)(NE / 4 / 256), 256, 0, stream>>>((float*)d_out, bo);
  gemm_out<<<dim3(Mdim / 128, DM / 128, 2), 256, 0, stream>>>(qc, Woc, (float*)d_out);
}

// Round 11
// 307.355 us; speedup vs baseline: 1.1342x; 1.0086x over previous
//
#include <hip/hip_runtime.h>
#include <hip/hip_bf16.h>

#define B_   2
#define S_   2048
#define DM   1024
#define NH   16
#define Mdim 4096
#define Kdim 1024

typedef __attribute__((ext_vector_type(8))) short bf16x8;
typedef __attribute__((ext_vector_type(4))) float f32x4;

__device__ __forceinline__ short f2b(float x) {
  union { __hip_bfloat16 h; short s; } u;
  u.h = __float2bfloat16(x);
  return u.s;
}

// Blocked GEMM operand layout: [row/128][k/32][row%128][k%32] (8 KB tiles).
__device__ __forceinline__ size_t blk_idx(int row, int k) {
  return ((size_t)(row >> 7) * 32 + (k >> 5)) * 4096 + (row & 127) * 32 + (k & 31);
}

// async global->LDS, 16 B/lane; LDS dst = wave-uniform base + lane*16
__device__ __forceinline__ void async_copy16(const void* g, void* l) {
  __builtin_amdgcn_global_load_lds(
      (const __attribute__((address_space(1))) unsigned int*)g,
      (__attribute__((address_space(3))) unsigned int*)l, 16, 0, 0);
}

// ---------------------------------------------------------------------------
// fp32 -> bf16 into blocked layout. thread t of tile tau handles
// (row = t>>1, k = (t&1)*16 .. +15) -> dst offset tau*4096 + 16*t (LINEAR).
struct Cvt7 {
  const float* src[7];
  ushort* dst[7];
  int n[7];
};

__global__ __launch_bounds__(256) void cvt_all(Cvt7 c) {
  const int ten = blockIdx.y;
  const int tau = blockIdx.x;
  if (tau >= (c.n[ten] >> 12)) return;
  const int t = threadIdx.x;
  const int row = (tau >> 5) * 128 + (t >> 1);
  const int k = (tau & 31) * 32 + (t & 1) * 16;
  const float* s = c.src[ten] + (size_t)row * 1024 + k;
  ushort* d = c.dst[ten] + (size_t)tau * 4096 + t * 16;
#pragma unroll
  for (int h = 0; h < 2; ++h) {
    float4 a = *(const float4*)(s + h * 8);
    float4 b = *(const float4*)(s + h * 8 + 4);
    bf16x8 r;
    r[0] = f2b(a.x); r[1] = f2b(a.y); r[2] = f2b(a.z); r[3] = f2b(a.w);
    r[4] = f2b(b.x); r[5] = f2b(b.y); r[6] = f2b(b.z); r[7] = f2b(b.w);
    *(bf16x8*)(d + h * 8) = r;
  }
}

// ---------------------------------------------------------------------------
// Pack mask to bits: mpk[(b*S+q)*32 + seg] = ballot over 64 keys.
__global__ __launch_bounds__(256) void pack_mask(const int* __restrict__ mask,
                                                 unsigned long long* __restrict__ mpk) {
  const int gw = (blockIdx.x * 256 + threadIdx.x) >> 6;
  const int lane = threadIdx.x & 63;
  const int mv = mask[(size_t)gw * 64 + lane];
  const unsigned long long bits = __ballot(mv != 0);
  if (lane == 0) mpk[gw] = bits;
}

// ---------------------------------------------------------------------------
// fill d_out with broadcast bias rows (before atomic split-K accumulation)
__global__ __launch_bounds__(256) void fill_bias(float* __restrict__ out,
                                                 const float* __restrict__ bias) {
  const int t = blockIdx.x * 256 + threadIdx.x;
  ((float4*)out)[t] = *(const float4*)&bias[(t * 4) & (DM - 1)];
}

// ---------------------------------------------------------------------------
// Merged Q/K/V projection GEMM (z selects tensor). 128x128, BK=32, dbuf,
// contiguous global_load_lds staging. 768 blocks = 3/CU.
struct Proj {
  const ushort* A[3];
  const ushort* W[3];
  const float* bias[3];
  ushort* out[3];
};

#define STAGE(buf, kb)                                  \
  do {                                                  \
    const size_t off = (size_t)(kb) * 4096;             \
    async_copy16(Ab + off, &a_s[buf][lo0]);             \
    async_copy16(Ab + off + 2048, &a_s[buf][lo1]);      \
    async_copy16(Wb + off, &b_s[buf][lo0]);             \
    async_copy16(Wb + off + 2048, &b_s[buf][lo1]);      \
  } while (0)

__global__ __launch_bounds__(256) void gemm_qkv(Proj p) {
  const int z = blockIdx.z;
  const int t = threadIdx.x;
  const int w = t >> 6, lane = t & 63;
  const int quad = lane >> 4, r16 = lane & 15;
  const int wr = w >> 1, wc = w & 1;
  const int row0 = blockIdx.x * 128, col0 = blockIdx.y * 128;

  __shared__ alignas(16) ushort a_s[2][4096];  // [row%128][k%32]
  __shared__ alignas(16) ushort b_s[2][4096];

  const ushort* Ab = p.A[z] + (size_t)blockIdx.x * 32 * 4096 + (size_t)t * 8;
  const ushort* Wb = p.W[z] + (size_t)blockIdx.y * 32 * 4096 + (size_t)t * 8;
  const int lo0 = w * 512, lo1 = 2048 + w * 512;

  f32x4 acc[4][4];
#pragma unroll
  for (int mt = 0; mt < 4; ++mt)
#pragma unroll
    for (int nt = 0; nt < 4; ++nt) acc[mt][nt] = (f32x4){0.f, 0.f, 0.f, 0.f};

  STAGE(0, 0);
  int cur = 0;
  for (int kb = 0; kb < 32; ++kb) {
    __syncthreads();
    if (kb + 1 < 32) STAGE(1 - cur, kb + 1);
    bf16x8 af[4], bfr[4];
#pragma unroll
    for (int mt = 0; mt < 4; ++mt)
      af[mt] = *(const bf16x8*)&a_s[cur][(wr * 64 + mt * 16 + r16) * 32 + quad * 8];
#pragma unroll
    for (int nt = 0; nt < 4; ++nt)
      bfr[nt] = *(const bf16x8*)&b_s[cur][(wc * 64 + nt * 16 + r16) * 32 + quad * 8];
#pragma unroll
    for (int mt = 0; mt < 4; ++mt)
#pragma unroll
      for (int nt = 0; nt < 4; ++nt)
        acc[mt][nt] = __builtin_amdgcn_mfma_f32_16x16x32_bf16(af[mt], bfr[nt],
                                                              acc[mt][nt], 0, 0, 0);
    cur ^= 1;
  }

  const float scale = (z == 0) ? 0.125f : 1.0f;
  ushort* Cv = p.out[z];
#pragma unroll
  for (int mt = 0; mt < 4; ++mt) {
#pragma unroll
    for (int nt = 0; nt < 4; ++nt) {
      const int col = col0 + wc * 64 + nt * 16 + r16;
      const float bv = p.bias[z][col];
      const int rowb = row0 + wr * 64 + mt * 16 + quad * 4;
#pragma unroll
      for (int i = 0; i < 4; ++i) {
        const float v = (acc[mt][nt][i] + bv) * scale;
        const int row = rowb + i;
        const int bb = row >> 11, s = row & (S_ - 1);
        const int hh = col >> 6, d = col & 63;
        if (z == 0) {
          Cv[(size_t)row * DM + col] = (ushort)f2b(v);
        } else if (z == 1) {
          // Kg[(bh*S+s)*64 + ((d/8)^(s&7))*8 + d&7]
          const size_t idx = ((size_t)(bb * NH + hh) * S_ + s) * 64 +
                             (((d >> 3) ^ (s & 7)) * 8) + (d & 7);
          Cv[idx] = (ushort)f2b(v);
        } else {
          // Vg: PV-slot permutation + xor swizzle, baked into global layout.
          // slot(key s6): K16=s6>>4, q4=(s6>>2)&3, i=s6&3
          //   pos = (K16>>1)*32 + q4*8 + (K16&1)*4 + i ; chunk c=pos>>3
          //   final = (c ^ (d&7))*8 + pos&7
          const int s6 = s & 63;
          const int K16 = s6 >> 4, q4 = (s6 >> 2) & 3, ii = s6 & 3;
          const int pos = (K16 >> 1) * 32 + q4 * 8 + (K16 & 1) * 4 + ii;
          const size_t idx = ((size_t)(bb * NH + hh) * 64 + d) * S_ + (s & ~63) +
                             (((pos >> 3) ^ (d & 7)) * 8) + (pos & 7);
          Cv[idx] = (ushort)f2b(v);
        }
      }
    }
  }
}

// ---------------------------------------------------------------------------
// Final GEMM, split-K=2 (512 blocks): atomics into bias-prefilled d_out.
__global__ __launch_bounds__(256) void gemm_out(const ushort* __restrict__ A,
                                                const ushort* __restrict__ W,
                                                float* __restrict__ out) {
  const int kz = blockIdx.z;
  const int t = threadIdx.x;
  const int w = t >> 6, lane = t & 63;
  const int quad = lane >> 4, r16 = lane & 15;
  const int wr = w >> 1, wc = w & 1;
  const int row0 = blockIdx.x * 128, col0 = blockIdx.y * 128;

  __shared__ alignas(16) ushort a_s[2][4096];
  __shared__ alignas(16) ushort b_s[2][4096];

  const ushort* Ab = A + (size_t)blockIdx.x * 32 * 4096 + (size_t)t * 8;
  const ushort* Wb = W + (size_t)blockIdx.y * 32 * 4096 + (size_t)t * 8;
  const int lo0 = w * 512, lo1 = 2048 + w * 512;

  f32x4 acc[4][4];
#pragma unroll
  for (int mt = 0; mt < 4; ++mt)
#pragma unroll
    for (int nt = 0; nt < 4; ++nt) acc[mt][nt] = (f32x4){0.f, 0.f, 0.f, 0.f};

  const int kb0 = kz * 16;
  STAGE(0, kb0);
  int cur = 0;
  for (int kb = kb0; kb < kb0 + 16; ++kb) {
    __syncthreads();
    if (kb + 1 < kb0 + 16) STAGE(1 - cur, kb + 1);
    bf16x8 af[4], bfr[4];
#pragma unroll
    for (int mt = 0; mt < 4; ++mt)
      af[mt] = *(const bf16x8*)&a_s[cur][(wr * 64 + mt * 16 + r16) * 32 + quad * 8];
#pragma unroll
    for (int nt = 0; nt < 4; ++nt)
      bfr[nt] = *(const bf16x8*)&b_s[cur][(wc * 64 + nt * 16 + r16) * 32 + quad * 8];
#pragma unroll
    for (int mt = 0; mt < 4; ++mt)
#pragma unroll
      for (int nt = 0; nt < 4; ++nt)
        acc[mt][nt] = __builtin_amdgcn_mfma_f32_16x16x32_bf16(af[mt], bfr[nt],
                                                              acc[mt][nt], 0, 0, 0);
    cur ^= 1;
  }
#undef STAGE

#pragma unroll
  for (int mt = 0; mt < 4; ++mt) {
#pragma unroll
    for (int nt = 0; nt < 4; ++nt) {
      const int col = col0 + wc * 64 + nt * 16 + r16;
      const int rowb = row0 + wr * 64 + mt * 16 + quad * 4;
#pragma unroll
      for (int i = 0; i < 4; ++i)
        unsafeAtomicAdd(&out[(size_t)(rowb + i) * DM + col], acc[mt][nt][i]);
    }
  }
}

// ---------------------------------------------------------------------------
// MFMA flash attention, S^T formulation: sacc = K·Q^T so each lane holds 16
// P-values of ONE q-row (r16) -> PV A-fragment built in-register (no LDS
// round-trip). Key permutation baked into Vg. No-max softmax (Q pre-scaled).
__global__ __launch_bounds__(256) void attn_mfma(const ushort* __restrict__ Qp,
                                                 const ushort* __restrict__ Kg,
                                                 const ushort* __restrict__ Vg,
                                                 const unsigned long long* __restrict__ mpk,
                                                 ushort* __restrict__ Oa) {
  const int bh = blockIdx.y;
  const int b = bh >> 4, h = bh & 15;
  const int q0 = blockIdx.x * 64;
  const int t = threadIdx.x;
  const int w = t >> 6, lane = t & 63, quad = lane >> 4, r16 = lane & 15;
  const size_t rb = (size_t)b * S_;

  __shared__ alignas(16) ushort k_s[64 * 64];
  __shared__ alignas(16) ushort vt_s[64 * 64];

  // Q fragments, used as the B-operand (n = qrow = r16)
  const ushort* qptr = Qp + (rb + q0 + w * 16 + r16) * DM + h * 64 + quad * 8;
  const bf16x8 bq0 = *(const bf16x8*)qptr;
  const bf16x8 bq1 = *(const bf16x8*)(qptr + 32);

  float l_lane = 0.f;
  f32x4 oacc[4];
#pragma unroll
  for (int nt = 0; nt < 4; ++nt) oacc[nt] = (f32x4){0.f, 0.f, 0.f, 0.f};

  const ushort* kgb = Kg + (size_t)bh * S_ * 64 + (size_t)t * 8;
  const ushort* vgb = Vg + (size_t)bh * 64 * S_ + (size_t)(t >> 3) * S_ + (t & 7) * 8;
  ushort* kl0 = &k_s[w * 512];
  ushort* kl1 = &k_s[2048 + w * 512];
  ushort* vl0 = &vt_s[w * 512];
  ushort* vl1 = &vt_s[2048 + w * 512];

  // one u64 of mask bits per 64-key tile, for THIS lane's q-row (r16)
  const unsigned long long* mrowp = mpk + (rb + q0 + w * 16 + r16) * 32;

  for (int kt = 0; kt < S_; kt += 64) {
    __syncthreads();
    async_copy16(kgb + (size_t)kt * 64, kl0);
    async_copy16(kgb + (size_t)(kt + 32) * 64, kl1);
    async_copy16(vgb + kt, vl0);
    async_copy16(vgb + (size_t)32 * S_ + kt, vl1);
    __syncthreads();

    // ---- S^T = K Q^T : sacc[mt] rows = keys mt*16+quad*4+i, col = qrow r16
    f32x4 sacc[4];
#pragma unroll
    for (int mt = 0; mt < 4; ++mt) {
      const int krow = mt * 16 + r16;
      const bf16x8 a0 = *(const bf16x8*)&k_s[krow * 64 + ((quad ^ (krow & 7)) * 8)];
      const bf16x8 a1 = *(const bf16x8*)&k_s[krow * 64 + (((4 + quad) ^ (krow & 7)) * 8)];
      f32x4 z = (f32x4){0.f, 0.f, 0.f, 0.f};
      z = __builtin_amdgcn_mfma_f32_16x16x32_bf16(a0, bq0, z, 0, 0, 0);
      sacc[mt] = __builtin_amdgcn_mfma_f32_16x16x32_bf16(a1, bq1, z, 0, 0, 0);
    }

    // ---- mask + exp; P stays in-register. key = mt*16 + quad*4 + i
    const unsigned long long mbits = mrowp[kt >> 6];
    bf16x8 pa0, pa1;
#pragma unroll
    for (int mt = 0; mt < 4; ++mt) {
#pragma unroll
      for (int i = 0; i < 4; ++i) {
        const unsigned int bit =
            (unsigned int)(mbits >> (mt * 16 + quad * 4 + i)) & 1u;
        const float p = bit ? __expf(sacc[mt][i]) : 0.f;
        l_lane += p;
        const short pb = f2b(p);
        if (mt < 2) pa0[(mt & 1) * 4 + i] = pb;
        else        pa1[(mt & 1) * 4 + i] = pb;
      }
    }

    // ---- O += P V (A = pa in-register; B = Vg slot-permuted tiles)
#pragma unroll
    for (int ks = 0; ks < 2; ++ks) {
      const bf16x8 pa = ks ? pa1 : pa0;
#pragma unroll
      for (int nt = 0; nt < 4; ++nt) {
        const int dk = nt * 16 + r16;
        const bf16x8 vb =
            *(const bf16x8*)&vt_s[dk * 64 + (((ks * 4 + quad) ^ (dk & 7)) * 8)];
        oacc[nt] = __builtin_amdgcn_mfma_f32_16x16x32_bf16(pa, vb, oacc[nt], 0, 0, 0);
      }
    }
  }

  // ---- epilogue: l[r16] = reduce over quad; broadcast to rows; store
  l_lane += __shfl_xor(l_lane, 16);
  l_lane += __shfl_xor(l_lane, 32);
#pragma unroll
  for (int i = 0; i < 4; ++i) {
    const float lq = __shfl(l_lane, quad * 4 + i);  // l of q-row quad*4+i
    const int row = (int)rb + q0 + w * 16 + quad * 4 + i;
#pragma unroll
    for (int nt = 0; nt < 4; ++nt) {
      const int col = h * 64 + nt * 16 + r16;
      Oa[blk_idx(row, col)] = (ushort)f2b(oacc[nt][i] / lq);
    }
  }
}

// ---------------------------------------------------------------------------
// Workspace = 56 MB (proven): qc,kc,vc | Qp,Kg,Vg | 4 weights.
// mpk (1 MB) overlays kc after projections consumed it (stream-ordered).
extern "C" void kernel_launch(void* const* d_in, const int* in_sizes, int n_in,
                              void* d_out, int out_size, void* d_ws, size_t ws_size,
                              hipStream_t stream) {
  const int* mask = (const int*)d_in[3];
  const float* bo = (const float*)d_in[11];

  const size_t NE = (size_t)B_ * S_ * DM;  // 4M
  const size_t NW = (size_t)DM * DM;       // 1M

  ushort* qc = (ushort*)d_ws;   // blocked
  ushort* kc = qc + NE;
  ushort* vc = kc + NE;
  ushort* Qp = vc + NE;         // [B*S, DM]
  ushort* Kg = Qp + NE;         // swizzled
  ushort* Vg = Kg + NE;         // slot-permuted + swizzled
  ushort* Wqc = Vg + NE;        // blocked weights
  ushort* Wkc = Wqc + NW;
  ushort* Wvc = Wkc + NW;
  ushort* Woc = Wvc + NW;
  unsigned long long* mpk = (unsigned long long*)kc;

  Cvt7 c;
  const int sidx[7] = {0, 1, 2, 4, 6, 8, 10};
  ushort* dsts[7] = {qc, kc, vc, Wqc, Wkc, Wvc, Woc};
  for (int i = 0; i < 7; ++i) {
    c.src[i] = (const float*)d_in[sidx[i]];
    c.dst[i] = dsts[i];
    c.n[i] = (i < 3) ? (int)NE : (int)NW;
  }
  cvt_all<<<dim3(1024, 7), 256, 0, stream>>>(c);

  Proj p;
  p.A[0] = qc;  p.A[1] = kc;  p.A[2] = vc;
  p.W[0] = Wqc; p.W[1] = Wkc; p.W[2] = Wvc;
  p.bias[0] = (const float*)d_in[5];
  p.bias[1] = (const float*)d_in[7];
  p.bias[2] = (const float*)d_in[9];
  p.out[0] = Qp; p.out[1] = Kg; p.out[2] = Vg;
  gemm_qkv<<<dim3(Mdim / 128, DM / 128, 3), 256, 0, stream>>>(p);

  pack_mask<<<(B_ * S_ * (S_ / 64) * 64) / 256, 256, 0, stream>>>(mask, mpk);

  attn_mfma<<<dim3(S_ / 64, B_ * NH), 256, 0, stream>>>(Qp, Kg, Vg, mpk, qc);

  fill_bias<<<(int)(NE / 4 / 256), 256, 0, stream>>>((float*)d_out, bo);
  gemm_out<<<dim3(Mdim / 128, DM / 128, 2), 256, 0, stream>>>(qc, Woc, (float*)d_out);
}

// Round 12
// 299.022 us; speedup vs baseline: 1.1659x; 1.0279x over previous
//
#include <hip/hip_runtime.h>
#include <hip/hip_bf16.h>

#define B_   2
#define S_   2048
#define DM   1024
#define NH   16
#define Mdim 4096

typedef __attribute__((ext_vector_type(8))) short bf16x8;
typedef __attribute__((ext_vector_type(4))) float f32x4;

__device__ __forceinline__ short f2b(float x) {
  union { __hip_bfloat16 h; short s; } u;
  u.h = __float2bfloat16(x);
  return u.s;
}

// Blocked GEMM operand layout: [row/128][k/32][row%128][k%32] (8 KB tiles).
__device__ __forceinline__ size_t blk_idx(int row, int k) {
  return ((size_t)(row >> 7) * 32 + (k >> 5)) * 4096 + (row & 127) * 32 + (k & 31);
}

// async global->LDS, 16 B/lane; LDS dst = wave-uniform base + lane*16
__device__ __forceinline__ void async_copy16(const void* g, void* l) {
  __builtin_amdgcn_global_load_lds(
      (const __attribute__((address_space(1))) unsigned int*)g,
      (__attribute__((address_space(3))) unsigned int*)l, 16, 0, 0);
}

// ---------------------------------------------------------------------------
// prep: y<7 -> fp32->bf16 cvt into blocked layout; y==7 -> fill d_out w/ bias.
struct Prep {
  const float* src[7];
  ushort* dst[7];
  int n[7];
  float* out;
  const float* bo;
};

__global__ __launch_bounds__(256) void prep(Prep p) {
  const int y = blockIdx.y, x = blockIdx.x, t = threadIdx.x;
  if (y < 7) {
    if (x >= (p.n[y] >> 12)) return;
    const int row = (x >> 5) * 128 + (t >> 1);
    const int k = (x & 31) * 32 + (t & 1) * 16;
    const float* s = p.src[y] + (size_t)row * 1024 + k;
    ushort* d = p.dst[y] + (size_t)x * 4096 + t * 16;
#pragma unroll
    for (int h = 0; h < 2; ++h) {
      float4 a = *(const float4*)(s + h * 8);
      float4 b = *(const float4*)(s + h * 8 + 4);
      bf16x8 r;
      r[0] = f2b(a.x); r[1] = f2b(a.y); r[2] = f2b(a.z); r[3] = f2b(a.w);
      r[4] = f2b(b.x); r[5] = f2b(b.y); r[6] = f2b(b.z); r[7] = f2b(b.w);
      *(bf16x8*)(d + h * 8) = r;
    }
  } else {
    const size_t t8 = ((size_t)x * 256 + t) * 8;  // 4M floats total
    const int col = (int)(t8 & (DM - 1));
    *(float4*)(p.out + t8) = *(const float4*)&p.bo[col];
    *(float4*)(p.out + t8 + 4) = *(const float4*)&p.bo[col + 4];
  }
}

// ---------------------------------------------------------------------------
// pack mask: thread handles 16 ints -> one ushort of bits (little-endian u64).
__global__ __launch_bounds__(256) void pack_mask(const int* __restrict__ mask,
                                                 ushort* __restrict__ mpk16) {
  const int g = blockIdx.x * 256 + threadIdx.x;  // 524288 ushorts
  const int4* m4 = (const int4*)(mask + (size_t)g * 16);
  unsigned int bits = 0;
#pragma unroll
  for (int q = 0; q < 4; ++q) {
    const int4 m = m4[q];
    bits |= (m.x != 0 ? 1u : 0u) << (q * 4 + 0);
    bits |= (m.y != 0 ? 1u : 0u) << (q * 4 + 1);
    bits |= (m.z != 0 ? 1u : 0u) << (q * 4 + 2);
    bits |= (m.w != 0 ? 1u : 0u) << (q * 4 + 3);
  }
  mpk16[g] = (ushort)bits;
}

// ---------------------------------------------------------------------------
#define STAGE(buf, kb)                                        \
  do {                                                        \
    const size_t off = (size_t)(kb) * 4096;                   \
    async_copy16(Ab + off, &smem[buf][lo0]);                  \
    async_copy16(Ab + off + 2048, &smem[buf][lo1]);           \
    async_copy16(Wb + off, &smem[buf][4096 + lo0]);           \
    async_copy16(Wb + off + 2048, &smem[buf][4096 + lo1]);    \
  } while (0)

// Merged Q/K/V projection GEMM (z selects tensor). 128x128, BK=32, dbuf,
// contiguous staging, LDS-staged coalesced epilogue. 768 blocks = 3/CU.
struct Proj {
  const ushort* A[3];
  const ushort* W[3];
  const float* bias[3];
  ushort* out[3];
};

__global__ __launch_bounds__(256) void gemm_qkv(Proj p) {
  const int z = blockIdx.z;
  const int t = threadIdx.x;
  const int w = t >> 6, lane = t & 63;
  const int quad = lane >> 4, r16 = lane & 15;
  const int wr = w >> 1, wc = w & 1;
  const int row0 = blockIdx.x * 128, col0 = blockIdx.y * 128;

  __shared__ alignas(16) ushort smem[2][8192];  // [buf][A:0..4095|B:4096..8191]

  const ushort* Ab = p.A[z] + (size_t)blockIdx.x * 32 * 4096 + (size_t)t * 8;
  const ushort* Wb = p.W[z] + (size_t)blockIdx.y * 32 * 4096 + (size_t)t * 8;
  const int lo0 = w * 512, lo1 = 2048 + w * 512;

  f32x4 acc[4][4];
#pragma unroll
  for (int mt = 0; mt < 4; ++mt)
#pragma unroll
    for (int nt = 0; nt < 4; ++nt) acc[mt][nt] = (f32x4){0.f, 0.f, 0.f, 0.f};

  STAGE(0, 0);
  int cur = 0;
  for (int kb = 0; kb < 32; ++kb) {
    __syncthreads();
    if (kb + 1 < 32) STAGE(1 - cur, kb + 1);
    bf16x8 af[4], bfr[4];
#pragma unroll
    for (int mt = 0; mt < 4; ++mt)
      af[mt] = *(const bf16x8*)&smem[cur][(wr * 64 + mt * 16 + r16) * 32 + quad * 8];
#pragma unroll
    for (int nt = 0; nt < 4; ++nt)
      bfr[nt] = *(const bf16x8*)&smem[cur][4096 + (wc * 64 + nt * 16 + r16) * 32 + quad * 8];
#pragma unroll
    for (int mt = 0; mt < 4; ++mt)
#pragma unroll
      for (int nt = 0; nt < 4; ++nt)
        acc[mt][nt] = __builtin_amdgcn_mfma_f32_16x16x32_bf16(af[mt], bfr[nt],
                                                              acc[mt][nt], 0, 0, 0);
    cur ^= 1;
  }

  // ---- epilogue: stage C tile in LDS in the final layout, then copy coalesced
  ushort* c_s = &smem[0][0];  // 16384 u16 = 32 KB
  const float scale = (z == 0) ? 0.125f : 1.0f;
  __syncthreads();
#pragma unroll
  for (int mt = 0; mt < 4; ++mt) {
#pragma unroll
    for (int nt = 0; nt < 4; ++nt) {
      const int c = wc * 64 + nt * 16 + r16;
      const float bv = p.bias[z][col0 + c];
#pragma unroll
      for (int i = 0; i < 4; ++i) {
        const int row = wr * 64 + mt * 16 + quad * 4 + i;
        const float v = (acc[mt][nt][i] + bv) * scale;
        int off;
        if (z == 0) {
          off = row * 128 + c;
        } else if (z == 1) {
          const int d = c & 63, hh = c >> 6;
          off = hh * 8192 + row * 64 + (((d >> 3) ^ (row & 7)) * 8) + (d & 7);
        } else {
          const int s6 = row & 63;
          const int pos = ((s6 >> 5) & 1) * 32 + ((s6 >> 2) & 3) * 8 +
                          ((s6 >> 4) & 1) * 4 + (s6 & 3);
          const int d = c & 63, hh = c >> 6, sb = row >> 6;
          off = (hh * 2 + sb) * 4096 + d * 64 + (((pos >> 3) ^ (d & 7)) * 8) + (pos & 7);
        }
        c_s[off] = (ushort)f2b(v);
      }
    }
  }
  __syncthreads();

  const int bb = row0 >> 11;       // batch
  const int s0 = row0 & (S_ - 1);  // seq base
  const int h0 = col0 >> 6;        // head base
  if (z == 0) {
    ushort* dst = p.out[0] + (size_t)row0 * DM + col0;
#pragma unroll
    for (int it = 0; it < 8; ++it) {
      const int lin = it * 256 + t, row = lin >> 4, ch = lin & 15;
      *(bf16x8*)(dst + (size_t)row * DM + ch * 8) = *(const bf16x8*)&c_s[row * 128 + ch * 8];
    }
  } else if (z == 1) {
#pragma unroll
    for (int it = 0; it < 8; ++it) {
      const int lin = it * 256 + t, hh = lin >> 10, wi = lin & 1023;
      ushort* dst = p.out[1] + ((size_t)(bb * NH + h0 + hh) * S_ + s0) * 64;
      *(bf16x8*)(dst + wi * 8) = *(const bf16x8*)&c_s[hh * 8192 + wi * 8];
    }
  } else {
#pragma unroll
    for (int it = 0; it < 8; ++it) {
      const int lin = it * 256 + t, reg = lin >> 9, wi = lin & 511;
      const int hh = reg >> 1, sb = reg & 1, d = wi >> 3, ko = (wi & 7) * 8;
      ushort* dst = p.out[2] + ((size_t)(bb * NH + h0 + hh) * 64 + d) * S_ +
                    s0 + sb * 64 + ko;
      *(bf16x8*)dst = *(const bf16x8*)&c_s[reg * 4096 + wi * 8];
    }
  }
}

// NOTE on Vg pos: round 11 used pos = (K16>>1)*32 + q4*8 + (K16&1)*4 + i with
// K16 = s6>>4 -> (K16>>1) = (s6>>5)&1; identical algebra above.

// ---------------------------------------------------------------------------
// Final GEMM, split-K=2 (512 blocks): atomics into bias-prefilled d_out.
__global__ __launch_bounds__(256) void gemm_out(const ushort* __restrict__ A,
                                                const ushort* __restrict__ W,
                                                float* __restrict__ out) {
  const int kz = blockIdx.z;
  const int t = threadIdx.x;
  const int w = t >> 6, lane = t & 63;
  const int quad = lane >> 4, r16 = lane & 15;
  const int wr = w >> 1, wc = w & 1;
  const int row0 = blockIdx.x * 128, col0 = blockIdx.y * 128;

  __shared__ alignas(16) ushort smem[2][8192];

  const ushort* Ab = A + (size_t)blockIdx.x * 32 * 4096 + (size_t)t * 8;
  const ushort* Wb = W + (size_t)blockIdx.y * 32 * 4096 + (size_t)t * 8;
  const int lo0 = w * 512, lo1 = 2048 + w * 512;

  f32x4 acc[4][4];
#pragma unroll
  for (int mt = 0; mt < 4; ++mt)
#pragma unroll
    for (int nt = 0; nt < 4; ++nt) acc[mt][nt] = (f32x4){0.f, 0.f, 0.f, 0.f};

  const int kb0 = kz * 16;
  STAGE(0, kb0);
  int cur = 0;
  for (int kb = kb0; kb < kb0 + 16; ++kb) {
    __syncthreads();
    if (kb + 1 < kb0 + 16) STAGE(1 - cur, kb + 1);
    bf16x8 af[4], bfr[4];
#pragma unroll
    for (int mt = 0; mt < 4; ++mt)
      af[mt] = *(const bf16x8*)&smem[cur][(wr * 64 + mt * 16 + r16) * 32 + quad * 8];
#pragma unroll
    for (int nt = 0; nt < 4; ++nt)
      bfr[nt] = *(const bf16x8*)&smem[cur][4096 + (wc * 64 + nt * 16 + r16) * 32 + quad * 8];
#pragma unroll
    for (int mt = 0; mt < 4; ++mt)
#pragma unroll
      for (int nt = 0; nt < 4; ++nt)
        acc[mt][nt] = __builtin_amdgcn_mfma_f32_16x16x32_bf16(af[mt], bfr[nt],
                                                              acc[mt][nt], 0, 0, 0);
    cur ^= 1;
  }
#undef STAGE

#pragma unroll
  for (int mt = 0; mt < 4; ++mt) {
#pragma unroll
    for (int nt = 0; nt < 4; ++nt) {
      const int col = col0 + wc * 64 + nt * 16 + r16;
      const int rowb = row0 + wr * 64 + mt * 16 + quad * 4;
#pragma unroll
      for (int i = 0; i < 4; ++i)
        unsafeAtomicAdd(&out[(size_t)(rowb + i) * DM + col], acc[mt][nt][i]);
    }
  }
}

// ---------------------------------------------------------------------------
// MFMA flash attention, S^T formulation + double-buffered K/V staging.
__global__ __launch_bounds__(256) void attn_mfma(const ushort* __restrict__ Qp,
                                                 const ushort* __restrict__ Kg,
                                                 const ushort* __restrict__ Vg,
                                                 const unsigned long long* __restrict__ mpk,
                                                 ushort* __restrict__ Oa) {
  const int bh = blockIdx.y;
  const int b = bh >> 4, h = bh & 15;
  const int q0 = blockIdx.x * 64;
  const int t = threadIdx.x;
  const int w = t >> 6, lane = t & 63, quad = lane >> 4, r16 = lane & 15;
  const size_t rb = (size_t)b * S_;

  __shared__ alignas(16) ushort k_s[2][4096];
  __shared__ alignas(16) ushort vt_s[2][4096];

  const ushort* qptr = Qp + (rb + q0 + w * 16 + r16) * DM + h * 64 + quad * 8;
  const bf16x8 bq0 = *(const bf16x8*)qptr;
  const bf16x8 bq1 = *(const bf16x8*)(qptr + 32);

  float l_lane = 0.f;
  f32x4 oacc[4];
#pragma unroll
  for (int nt = 0; nt < 4; ++nt) oacc[nt] = (f32x4){0.f, 0.f, 0.f, 0.f};

  const ushort* kgb = Kg + (size_t)bh * S_ * 64 + (size_t)t * 8;
  const ushort* vgb = Vg + (size_t)bh * 64 * S_ + (size_t)(t >> 3) * S_ + (t & 7) * 8;

#define ASTAGE(buf, kt)                                                   \
  do {                                                                    \
    async_copy16(kgb + (size_t)(kt) * 64, &k_s[buf][w * 512]);            \
    async_copy16(kgb + (size_t)((kt) + 32) * 64, &k_s[buf][2048 + w * 512]); \
    async_copy16(vgb + (kt), &vt_s[buf][w * 512]);                        \
    async_copy16(vgb + (size_t)32 * S_ + (kt), &vt_s[buf][2048 + w * 512]); \
  } while (0)

  const unsigned long long* mrowp = mpk + (rb + q0 + w * 16 + r16) * 32;

  ASTAGE(0, 0);
  int cur = 0;
  for (int kt = 0; kt < S_; kt += 64) {
    __syncthreads();
    if (kt + 64 < S_) ASTAGE(cur ^ 1, kt + 64);

    // ---- S^T = K Q^T : rows = keys mt*16+quad*4+i, col = qrow r16
    f32x4 sacc[4];
#pragma unroll
    for (int mt = 0; mt < 4; ++mt) {
      const int krow = mt * 16 + r16;
      const bf16x8 a0 = *(const bf16x8*)&k_s[cur][krow * 64 + ((quad ^ (krow & 7)) * 8)];
      const bf16x8 a1 = *(const bf16x8*)&k_s[cur][krow * 64 + (((4 + quad) ^ (krow & 7)) * 8)];
      f32x4 zz = (f32x4){0.f, 0.f, 0.f, 0.f};
      zz = __builtin_amdgcn_mfma_f32_16x16x32_bf16(a0, bq0, zz, 0, 0, 0);
      sacc[mt] = __builtin_amdgcn_mfma_f32_16x16x32_bf16(a1, bq1, zz, 0, 0, 0);
    }

    // ---- mask + exp; P stays in-register. key = mt*16 + quad*4 + i
    const unsigned long long mbits = mrowp[kt >> 6];
    bf16x8 pa0, pa1;
#pragma unroll
    for (int mt = 0; mt < 4; ++mt) {
#pragma unroll
      for (int i = 0; i < 4; ++i) {
        const unsigned int bit =
            (unsigned int)(mbits >> (mt * 16 + quad * 4 + i)) & 1u;
        const float p = bit ? __expf(sacc[mt][i]) : 0.f;
        l_lane += p;
        const short pb = f2b(p);
        if (mt < 2) pa0[(mt & 1) * 4 + i] = pb;
        else        pa1[(mt & 1) * 4 + i] = pb;
      }
    }

    // ---- O += P V
#pragma unroll
    for (int ks = 0; ks < 2; ++ks) {
      const bf16x8 pa = ks ? pa1 : pa0;
#pragma unroll
      for (int nt = 0; nt < 4; ++nt) {
        const int dk = nt * 16 + r16;
        const bf16x8 vb =
            *(const bf16x8*)&vt_s[cur][dk * 64 + (((ks * 4 + quad) ^ (dk & 7)) * 8)];
        oacc[nt] = __builtin_amdgcn_mfma_f32_16x16x32_bf16(pa, vb, oacc[nt], 0, 0, 0);
      }
    }
    cur ^= 1;
  }
#undef ASTAGE

  // ---- epilogue: reduce l over quads; broadcast per row; store blocked
  l_lane += __shfl_xor(l_lane, 16);
  l_lane += __shfl_xor(l_lane, 32);
#pragma unroll
  for (int i = 0; i < 4; ++i) {
    const float lq = __shfl(l_lane, quad * 4 + i);
    const int row = (int)rb + q0 + w * 16 + quad * 4 + i;
#pragma unroll
    for (int nt = 0; nt < 4; ++nt) {
      const int col = h * 64 + nt * 16 + r16;
      Oa[blk_idx(row, col)] = (ushort)f2b(oacc[nt][i] / lq);
    }
  }
}

// ---------------------------------------------------------------------------
// Workspace = 56 MB: qc,kc,vc | Qp,Kg,Vg | 4 weights.
// mpk (1 MB) overlays kc after gemm_qkv consumed it (stream-ordered).
extern "C" void kernel_launch(void* const* d_in, const int* in_sizes, int n_in,
                              void* d_out, int out_size, void* d_ws, size_t ws_size,
                              hipStream_t stream) {
  const int* mask = (const int*)d_in[3];

  const size_t NE = (size_t)B_ * S_ * DM;  // 4M
  const size_t NW = (size_t)DM * DM;       // 1M

  ushort* qc = (ushort*)d_ws;   // blocked (later: attn out)
  ushort* kc = qc + NE;
  ushort* vc = kc + NE;
  ushort* Qp = vc + NE;         // [B*S, DM]
  ushort* Kg = Qp + NE;         // swizzled
  ushort* Vg = Kg + NE;         // slot-permuted + swizzled
  ushort* Wqc = Vg + NE;        // blocked weights
  ushort* Wkc = Wqc + NW;
  ushort* Wvc = Wkc + NW;
  ushort* Woc = Wvc + NW;
  unsigned long long* mpk = (unsigned long long*)kc;

  Prep pr;
  const int sidx[7] = {0, 1, 2, 4, 6, 8, 10};
  ushort* dsts[7] = {qc, kc, vc, Wqc, Wkc, Wvc, Woc};
  for (int i = 0; i < 7; ++i) {
    pr.src[i] = (const float*)d_in[sidx[i]];
    pr.dst[i] = dsts[i];
    pr.n[i] = (i < 3) ? (int)NE : (int)NW;
  }
  pr.out = (float*)d_out;
  pr.bo = (const float*)d_in[11];
  prep<<<dim3(2048, 8), 256, 0, stream>>>(pr);

  Proj p;
  p.A[0] = qc;  p.A[1] = kc;  p.A[2] = vc;
  p.W[0] = Wqc; p.W[1] = Wkc; p.W[2] = Wvc;
  p.bias[0] = (const float*)d_in[5];
  p.bias[1] = (const float*)d_in[7];
  p.bias[2] = (const float*)d_in[9];
  p.out[0] = Qp; p.out[1] = Kg; p.out[2] = Vg;
  gemm_qkv<<<dim3(Mdim / 128, DM / 128, 3), 256, 0, stream>>>(p);

  pack_mask<<<2048, 256, 0, stream>>>(mask, (ushort*)mpk);

  attn_mfma<<<dim3(S_ / 64, B_ * NH), 256, 0, stream>>>(Qp, Kg, Vg, mpk, qc);

  gemm_out<<<dim3(Mdim / 128, DM / 128, 2), 256, 0, stream>>>(qc, Woc, (float*)d_out);
}